// Round 12
// baseline (261.728 us; speedup 1.0000x reference)
//
#include <hip/hip_runtime.h>
#include <stdint.h>

typedef unsigned short u16;
typedef unsigned int   u32;

#define NG   512
#define NPG  200
#define EPG  6400
#define NN   (NG*NPG)
#define NE_  (NG*EPG)
#define HID  128
#define KP   224          // h1sT padded K (global, no bank concern)
#define AQS  232          // Aq LDS row stride u16 (conflict-free A-frags)
#define ZP   136          // Zq row stride u16
#define QCAP 2048         // edge bucket capacity per (g, quarter)

__device__ __forceinline__ float bf2f(u16 b){ u32 u = ((u32)b) << 16; return __builtin_bit_cast(float, u); }
__device__ __forceinline__ u16 f2bf(float f){
    u32 u = __builtin_bit_cast(u32, f);
    u = (u + 0x7FFFu + ((u >> 16) & 1u)) >> 16;
    return (u16)u;
}

typedef __attribute__((ext_vector_type(8))) short bf16x8;
typedef __attribute__((ext_vector_type(4))) float f32x4;

enum : int { cW1=0, cb1=128, cb2=256, cba=384, cbb=896, cbc=1920, cbd=2944, cWe=3456, cbe=8576, cEND=8586 };
enum : int { T_Wa=0, T_Wb=65536, T_Wc=589824, T_Wd=1638400, T_END=2162688 };

// ---------------------------------------------------------------------------
// K_prep2: LDS-tiled weight transposes + canon vectors + hg zeroing.
// ---------------------------------------------------------------------------
struct PrepIn { const void* p[14]; };

__global__ __launch_bounds__(256) void k_prep2(PrepIn in, float* __restrict__ canon,
                                               u16* __restrict__ W2T, u16* __restrict__ WTa,
                                               float* __restrict__ hg)
{
    __shared__ u16 tile[64][72];
    __shared__ int sflag;
    const int tid = threadIdx.x;
    if (tid < 64){
        const u16* wb = (const u16*)in.p[0];
        u16 a = wb[tid], b = wb[64 + tid];
        unsigned long long m1 = __ballot((int)((a >> 7) & 0xFF) >= 0x7F);
        unsigned long long m2 = __ballot((int)((b >> 7) & 0xFF) >= 0x7F);
        if (tid == 0) sflag = (__popcll(m1) + __popcll(m2) > 4) ? 1 : 0;
    }
    __syncthreads();
    const int f = sflag;
    const int bid = blockIdx.x;

    // every block zeroes a 116-float slice of hg (566*116 >= 65536)
    if (tid < 116){
        int j = bid*116 + tid;
        if (j < NG*HID) hg[j] = 0.f;
    }

    if (bid < 532){
        const void* s; u16* dst; int K, N, t, lgn;
        if      (bid < 4)  { t = bid;       s = in.p[2];  dst = W2T;        K = 128;  N = 128;  lgn = 1; }
        else if (bid < 20) { t = bid - 4;   s = in.p[4];  dst = WTa + T_Wa; K = 128;  N = 512;  lgn = 3; }
        else if (bid < 148){ t = bid - 20;  s = in.p[6];  dst = WTa + T_Wb; K = 512;  N = 1024; lgn = 4; }
        else if (bid < 404){ t = bid - 148; s = in.p[8];  dst = WTa + T_Wc; K = 1024; N = 1024; lgn = 4; }
        else               { t = bid - 404; s = in.p[10]; dst = WTa + T_Wd; K = 1024; N = 512;  lgn = 3; }
        const int k0 = (t >> lgn) * 64, n0 = (t & ((1 << lgn) - 1)) * 64;
        #pragma unroll
        for (int i = 0; i < 16; i++){
            int idx = i*256 + tid;
            int kk = idx >> 6, nn = idx & 63;
            int si = (k0 + kk)*N + n0 + nn;
            tile[nn][kk] = f ? f2bf(((const float*)s)[si]) : ((const u16*)s)[si];
        }
        __syncthreads();
        #pragma unroll
        for (int i = 0; i < 16; i++){
            int idx = i*256 + tid;
            int nn = idx >> 6, kk = idx & 63;
            dst[(size_t)(n0 + nn)*K + k0 + kk] = tile[nn][kk];
        }
    } else {
        int i = (bid - 532)*256 + tid;
        if (i < cEND){
            const void* s; int off;
            if      (i < 128) { s = in.p[0];  off = i; }
            else if (i < 256) { s = in.p[1];  off = i - 128; }
            else if (i < 384) { s = in.p[3];  off = i - 256; }
            else if (i < 896) { s = in.p[5];  off = i - 384; }
            else if (i < 1920){ s = in.p[7];  off = i - 896; }
            else if (i < 2944){ s = in.p[9];  off = i - 1920; }
            else if (i < 3456){ s = in.p[11]; off = i - 2944; }
            else if (i < 8576){ s = in.p[12]; off = i - 3456; }
            else              { s = in.p[13]; off = i - 8576; }
            canon[i] = f ? ((const float*)s)[off] : bf2f(((const u16*)s)[off]);
        }
    }
}

// ---------------------------------------------------------------------------
// K_l1: per graph (256 thr): degrees, invIn, rank-1 layer-1 -> h1sT (global,
// io folded), quarter-bucketed edge lists. sAgg replicated x4 vs contention.
// ---------------------------------------------------------------------------
__global__ __launch_bounds__(256) void k_l1(
    const int* __restrict__ src, const int* __restrict__ dst,
    const float* __restrict__ W1, const float* __restrict__ b1,
    float* __restrict__ invInG, u16* __restrict__ h1sT,
    u32* __restrict__ edgeBuf, int* __restrict__ cntQ)
{
    __shared__ u16 srcL[EPG];
    __shared__ u16 dstL[EPG];
    __shared__ int degIn[NPG], degOut[NPG];
    __shared__ int qcur[4];
    __shared__ float sAgg4[4][NPG];
    __shared__ float sValL[NPG], iiL[NPG], ioL[NPG], tL[NPG];
    __shared__ float w1L[HID], b1L[HID];

    const int g = blockIdx.x, tid = threadIdx.x;

    if (tid < NPG){
        degIn[tid] = 0; degOut[tid] = 0;
        sAgg4[0][tid] = 0.f; sAgg4[1][tid] = 0.f; sAgg4[2][tid] = 0.f; sAgg4[3][tid] = 0.f;
    }
    if (tid < HID){ w1L[tid] = W1[tid]; b1L[tid] = b1[tid]; }
    if (tid < 4) qcur[tid] = 0;
    __syncthreads();

    const int ebase = g * EPG;
    #pragma unroll
    for (int i = 0; i < EPG/256; i++){
        int e = i*256 + tid;
        int s = src[ebase + e] - g*NPG;
        int d = dst[ebase + e] - g*NPG;
        srcL[e] = (u16)s; dstL[e] = (u16)d;
        atomicAdd(&degOut[s], 1);
        atomicAdd(&degIn[d], 1);
    }
    __syncthreads();

    if (tid < NPG){
        float ii = rsqrtf(fmaxf((float)degIn[tid], 1.f));
        float io = rsqrtf(fmaxf((float)degOut[tid], 1.f));
        iiL[tid] = ii; ioL[tid] = io;
        sValL[tid] = (float)degIn[tid] * io;     // h0 = in_deg; s = h0*inv_out
        invInG[g*NPG + tid] = ii;
    }
    __syncthreads();

    // layer-1 aggregation (x4-replicated) + quarter bucket scatter
    const int rep = tid & 3;
    #pragma unroll
    for (int i = 0; i < EPG/256; i++){
        int e = i*256 + tid;
        int s = srcL[e], d = dstL[e];
        atomicAdd(&sAgg4[rep][d], sValL[s]);
        int q = (d * 41) >> 11;                  // exact d/50, d in [0,200)
        int pos = atomicAdd(&qcur[q], 1);
        if (pos < QCAP)
            edgeBuf[((size_t)(g*4 + q))*QCAP + pos] = (u32)s | ((u32)(d - q*50) << 16);
    }
    __syncthreads();

    if (tid < 4) cntQ[g*4 + tid] = (qcur[tid] < QCAP) ? qcur[tid] : QCAP;
    if (tid < NPG)
        tL[tid] = (sAgg4[0][tid] + sAgg4[1][tid] + sAgg4[2][tid] + sAgg4[3][tid]) * iiL[tid];
    __syncthreads();

    // h1sT[c][v] = bf16( relu(t*w1+b1) * io ), v padded to KP
    const size_t base = (size_t)g * HID * KP;
    #pragma unroll 4
    for (int i = 0; i < HID*KP/256; i++){
        int idx = i*256 + tid;
        int c = idx / KP, v = idx - c*KP;
        u16 o = 0;
        if (v < NPG)
            o = f2bf(fmaxf(fmaf(tL[v], w1L[c], b1L[c]), 0.f) * ioL[v]);
        h1sT[base + idx] = o;
    }
}

// ---------------------------------------------------------------------------
// K_quarter: block = (g, q) XCD-swizzled, 256 thr = 4 waves, ~32 KB LDS.
//  Build Aq (64xAQS) from bucket; GEMM1 Z = Aq @ h1s^T (A from LDS, B ring-3
//  from global); Zq unions Aq; GEMM2 H = Zq @ W2; pooled epilogue -> hg atomic.
// A-frag: A[m=lr][k=quad*8+j]; B-frag: B[k=quad*8+j][n=lr]; C/D: col=lr,row=quad*4+r
// ---------------------------------------------------------------------------
__global__ __launch_bounds__(256, 5) void k_quarter(
    const u32* __restrict__ edgeBuf, const int* __restrict__ cntQ,
    const u16* __restrict__ h1sT, const u16* __restrict__ W2T,
    const float* __restrict__ invInG, const float* __restrict__ b2,
    float* __restrict__ hg)
{
    __shared__ __align__(16) u16 Aq[64*AQS];     // 29.7 KB; Zq (64xZP) unions it
    __shared__ float invInL[64];
    __shared__ float b2L[HID];
    __shared__ float poolL[HID];

    const int bid = blockIdx.x, tid = threadIdx.x;
    const int xcd = bid & 7, slot = bid >> 3;
    const int g = (slot >> 2) * 8 + xcd;         // 4 quarters of g on one XCD
    const int q = slot & 3;
    u32* aq32 = (u32*)Aq;

    if (tid < HID){ b2L[tid] = b2[tid]; poolL[tid] = 0.f; }
    if (tid < 64) invInL[tid] = (tid < 50) ? invInG[g*NPG + q*50 + tid] : 0.f;

    // zero Aq
    uint4* a4 = (uint4*)Aq;
    #pragma unroll
    for (int i = 0; i < 8; i++){
        int idx = i*256 + tid;
        if (idx < 64*AQS/8) a4[idx] = make_uint4(0,0,0,0);
    }
    __syncthreads();

    // scatter bucket counts (u32-packed u16 atomics)
    const int cnt = cntQ[g*4 + q];
    const u32* eb = edgeBuf + (size_t)(g*4 + q) * QCAP;
    for (int i = tid; i < cnt; i += 256){
        u32 e = eb[i];
        int idx = (int)(e >> 16) * AQS + (int)(e & 0xFFFF);
        atomicAdd(&aq32[idx >> 1], 1u << (16*(idx & 1)));
    }
    __syncthreads();

    // counts -> bf16 in place (small ints: exact)
    for (int i = tid; i < 64*AQS/2; i += 256){
        u32 wv = aq32[i];
        if (wv)
            aq32[i] = (u32)f2bf((float)(wv & 0xFFFFu)) | ((u32)f2bf((float)(wv >> 16)) << 16);
    }
    __syncthreads();

    const int w = tid >> 6, lane = tid & 63;
    const int wm = w >> 1, wn = w & 1;
    const int lr = lane & 15, quad = lane >> 4;
    const f32x4 fz = {0.f, 0.f, 0.f, 0.f};

    // ---- GEMM1: Z[vq][c] = Aq(64x224) @ B, B[k=v'][n=c] = h1sT[g][c][v']
    f32x4 acc[2][4];
    #pragma unroll
    for (int mi = 0; mi < 2; mi++)
        #pragma unroll
        for (int nt = 0; nt < 4; nt++) acc[mi][nt] = fz;
    {
        const u16* Bg = h1sT + (size_t)g * HID * KP + (size_t)(wn*64) * KP;
        bf16x8 br[3][4];
        #pragma unroll
        for (int nt = 0; nt < 4; nt++){
            br[0][nt] = *(const bf16x8*)&Bg[(nt*16 + lr)*KP + quad*8];
            br[1][nt] = *(const bf16x8*)&Bg[(nt*16 + lr)*KP + 32 + quad*8];
        }
        #pragma unroll
        for (int ks = 0; ks < 7; ks++){
            const int sl = ks % 3, pf = (ks + 2) % 3;
            if (ks + 2 < 7){
                #pragma unroll
                for (int nt = 0; nt < 4; nt++)
                    br[pf][nt] = *(const bf16x8*)&Bg[(nt*16 + lr)*KP + (ks+2)*32 + quad*8];
            }
            bf16x8 af[2];
            #pragma unroll
            for (int mi = 0; mi < 2; mi++)
                af[mi] = *(const bf16x8*)&Aq[((wm*2 + mi)*16 + lr)*AQS + ks*32 + quad*8];
            #pragma unroll
            for (int mi = 0; mi < 2; mi++)
                #pragma unroll
                for (int nt = 0; nt < 4; nt++)
                    acc[mi][nt] = __builtin_amdgcn_mfma_f32_16x16x32_bf16(
                        af[mi], br[sl][nt], acc[mi][nt], 0, 0, 0);
        }
    }
    __syncthreads();   // Aq reads done -> reuse as Zq

    // write Zq[vq][c]
    u16* Zq = Aq;
    #pragma unroll
    for (int mi = 0; mi < 2; mi++)
        #pragma unroll
        for (int nt = 0; nt < 4; nt++){
            int vq = (wm*2 + mi)*16 + quad*4;
            int c = wn*64 + nt*16 + lr;
            Zq[(vq+0)*ZP + c] = f2bf(acc[mi][nt][0]);
            Zq[(vq+1)*ZP + c] = f2bf(acc[mi][nt][1]);
            Zq[(vq+2)*ZP + c] = f2bf(acc[mi][nt][2]);
            Zq[(vq+3)*ZP + c] = f2bf(acc[mi][nt][3]);
        }
    __syncthreads();

    // ---- GEMM2: H[vq][cout] = Zq(64x128) @ W2, B[k=cin][n=cout] = W2T[cout][cin]
    f32x4 acc2[2][4];
    #pragma unroll
    for (int mi = 0; mi < 2; mi++)
        #pragma unroll
        for (int nt = 0; nt < 4; nt++) acc2[mi][nt] = fz;
    {
        const u16* Wg = W2T + (size_t)(wn*64) * HID;
        bf16x8 bcur[4], bnxt[4];
        #pragma unroll
        for (int nt = 0; nt < 4; nt++)
            bcur[nt] = *(const bf16x8*)&Wg[(nt*16 + lr)*HID + quad*8];
        #pragma unroll
        for (int ks = 0; ks < 4; ks++){
            if (ks < 3){
                #pragma unroll
                for (int nt = 0; nt < 4; nt++)
                    bnxt[nt] = *(const bf16x8*)&Wg[(nt*16 + lr)*HID + (ks+1)*32 + quad*8];
            }
            bf16x8 za[2];
            #pragma unroll
            for (int mi = 0; mi < 2; mi++)
                za[mi] = *(const bf16x8*)&Zq[((wm*2 + mi)*16 + lr)*ZP + ks*32 + quad*8];
            #pragma unroll
            for (int mi = 0; mi < 2; mi++)
                #pragma unroll
                for (int nt = 0; nt < 4; nt++)
                    acc2[mi][nt] = __builtin_amdgcn_mfma_f32_16x16x32_bf16(
                        za[mi], bcur[nt], acc2[mi][nt], 0, 0, 0);
            #pragma unroll
            for (int nt = 0; nt < 4; nt++) bcur[nt] = bnxt[nt];
        }
    }

    // epilogue: h2 = relu(H*invIn + b2); pool; hg global atomic
    #pragma unroll
    for (int mi = 0; mi < 2; mi++)
        #pragma unroll
        for (int nt = 0; nt < 4; nt++){
            int cout = wn*64 + nt*16 + lr;
            float s = 0.f;
            #pragma unroll
            for (int r = 0; r < 4; r++){
                int vq = (wm*2 + mi)*16 + quad*4 + r;
                if (vq < 50)
                    s += fmaxf(fmaf(acc2[mi][nt][r], invInL[vq], b2L[cout]), 0.f);
            }
            atomicAdd(&poolL[cout], s);
        }
    __syncthreads();
    if (tid < HID) atomicAdd(&hg[(size_t)g*HID + tid], poolL[tid] * (1.f / NPG));
}

// ---------------------------------------------------------------------------
// K_mlp6: 32x32 tiles, 512 thr = 8 waves (2kz x 2wm x 2wn), ring-3 prefetch,
// 2x block count vs mlp5 for TLP. hi/lo bf16 split (fp32-accurate).
// ---------------------------------------------------------------------------
template<int K, bool AF32>
__global__ __launch_bounds__(512) void k_mlp6(
    const void* __restrict__ Ahi_, const u16* __restrict__ Alo,
    const u16* __restrict__ WT, const float* __restrict__ bias,
    u16* __restrict__ Ohi, u16* __restrict__ Olo, int Nc)
{
    constexpr int ITERS = K / 64;
    __shared__ __align__(16) float red[32][36];

    const int tid = threadIdx.x;
    const int w = tid >> 6, lane = tid & 63;
    const int kz = w >> 2, wm = (w >> 1) & 1, wn = w & 1;
    const int lr = lane & 15, quad = lane >> 4;
    const int row0 = blockIdx.x * 32, col0 = blockIdx.y * 32;
    const int m = row0 + wm*16 + lr;
    const int n = col0 + wn*16 + lr;
    const int k0 = kz * (K/2);

    const float* Af = (const float*)Ahi_;
    const u16*   Ah = (const u16*)Ahi_;

    auto loadA = [&](int it, bf16x8& hi, bf16x8& lo){
        const int kk = k0 + it*32 + quad*8;
        if constexpr (AF32){
            float xs[8];
            *(float4*)&xs[0] = *(const float4*)&Af[(size_t)m*K + kk];
            *(float4*)&xs[4] = *(const float4*)&Af[(size_t)m*K + kk + 4];
            #pragma unroll
            for (int j = 0; j < 8; j++){
                u16 hh = f2bf(xs[j]);
                hi[j] = (short)hh;
                lo[j] = (short)f2bf(xs[j] - bf2f(hh));
            }
        } else {
            hi = *(const bf16x8*)&Ah[(size_t)m*K + kk];
            lo = *(const bf16x8*)&Alo[(size_t)m*K + kk];
        }
    };

    const f32x4 fz = {0.f, 0.f, 0.f, 0.f};
    f32x4 acc = fz;
    bf16x8 hi[3], lo[3], bb[3];
    loadA(0, hi[0], lo[0]);
    bb[0] = *(const bf16x8*)&WT[(size_t)n*K + k0 + quad*8];
    if (ITERS > 1){
        loadA(1, hi[1], lo[1]);
        bb[1] = *(const bf16x8*)&WT[(size_t)n*K + k0 + 32 + quad*8];
    }
    #pragma unroll
    for (int it = 0; it < ITERS; it++){
        const int sl = it % 3, pf = (it + 2) % 3;
        if (it + 2 < ITERS){
            loadA(it+2, hi[pf], lo[pf]);
            bb[pf] = *(const bf16x8*)&WT[(size_t)n*K + k0 + (it+2)*32 + quad*8];
        }
        acc = __builtin_amdgcn_mfma_f32_16x16x32_bf16(hi[sl], bb[sl], acc, 0, 0, 0);
        acc = __builtin_amdgcn_mfma_f32_16x16x32_bf16(lo[sl], bb[sl], acc, 0, 0, 0);
    }

    if (kz == 1){
        #pragma unroll
        for (int r = 0; r < 4; r++)
            red[wm*16 + quad*4 + r][wn*16 + lr] = acc[r];
    }
    __syncthreads();
    if (kz == 0){
        #pragma unroll
        for (int r = 0; r < 4; r++){
            int rr = wm*16 + quad*4 + r;
            int cc = wn*16 + lr;
            float v = acc[r] + red[rr][cc] + bias[col0 + cc];
            v = fmaxf(v, 0.f);
            u16 hh = f2bf(v);
            size_t go = (size_t)(row0 + rr) * Nc + col0 + cc;
            Ohi[go] = hh;
            Olo[go] = f2bf(v - bf2f(hh));
        }
    }
}

// ---------------------------------------------------------------------------
// head: logits = (X4hi+X4lo) @ We + be; softmax -> out
// ---------------------------------------------------------------------------
__global__ __launch_bounds__(64) void k_head(
    const u16* __restrict__ Xhi, const u16* __restrict__ Xlo,
    const float* __restrict__ We, const float* __restrict__ be,
    void* __restrict__ out, const u16* __restrict__ w1bits)
{
    const int g = blockIdx.x, lane = threadIdx.x;
    u16 a = w1bits[lane], b = w1bits[64 + lane];
    unsigned long long m1 = __ballot((int)((a >> 7) & 0xFF) >= 0x7F);
    unsigned long long m2 = __ballot((int)((b >> 7) & 0xFF) >= 0x7F);
    const int f = (__popcll(m1) + __popcll(m2) > 4) ? 1 : 0;

    float part[10];
    #pragma unroll
    for (int c = 0; c < 10; c++) part[c] = 0.f;
    for (int k = lane; k < 512; k += 64){
        float x = bf2f(Xhi[(size_t)g*512 + k]) + bf2f(Xlo[(size_t)g*512 + k]);
        #pragma unroll
        for (int c = 0; c < 10; c++) part[c] = fmaf(x, We[k*10 + c], part[c]);
    }
    #pragma unroll
    for (int c = 0; c < 10; c++){
        float v = part[c];
        for (int off = 32; off > 0; off >>= 1) v += __shfl_down(v, off);
        part[c] = v;
    }
    if (lane == 0){
        #pragma unroll
        for (int c = 0; c < 10; c++) part[c] += be[c];
        float m = part[0];
        #pragma unroll
        for (int c = 1; c < 10; c++) m = fmaxf(m, part[c]);
        float e[10], s = 0.f;
        #pragma unroll
        for (int c = 0; c < 10; c++){ e[c] = __expf(part[c] - m); s += e[c]; }
        float inv = 1.f / s;
        #pragma unroll
        for (int c = 0; c < 10; c++){
            float p = e[c] * inv;
            if (f) ((float*)out)[g*10 + c] = p;
            else   ((u16*)out)[g*10 + c]  = f2bf(p);
        }
    }
}

// ---------------------------------------------------------------------------
extern "C" void kernel_launch(void* const* d_in, const int* in_sizes, int n_in,
                              void* d_out, int out_size, void* d_ws, size_t ws_size,
                              hipStream_t stream)
{
    const int* src = (const int*)d_in[0];
    const int* dst = (const int*)d_in[1];

    char* ws = (char*)d_ws;
    size_t o = 0;
    float* canon    = (float*)(ws + o); o += ((size_t)cEND * 4 + 15) & ~(size_t)15;
    u16*   W2T      = (u16*)  (ws + o); o += (size_t)HID * HID * 2;
    u16*   WTa      = (u16*)  (ws + o); o += ((size_t)T_END * 2 + 15) & ~(size_t)15;
    float* invIn    = (float*)(ws + o); o += (size_t)NN * 4;
    u32*   edgeBuf  = (u32*)  (ws + o); o += (size_t)NG * 4 * QCAP * 4;   // 16.8 MB
    int*   cntQ     = (int*)  (ws + o); o += (size_t)NG * 4 * 4;
    u16*   h1sT     = (u16*)  (ws + o); o += (size_t)NG * HID * KP * 2;   // 29.4 MB
    float* hg       = (float*)(ws + o); o += (size_t)NG * HID * 4;
    u16*   X1hi     = (u16*)  (ws + o); o += (size_t)NG * 512 * 2;
    u16*   X1lo     = (u16*)  (ws + o); o += (size_t)NG * 512 * 2;
    u16*   X2hi     = (u16*)  (ws + o); o += (size_t)NG * 1024 * 2;
    u16*   X2lo     = (u16*)  (ws + o); o += (size_t)NG * 1024 * 2;
    u16*   X3hi     = (u16*)  (ws + o); o += (size_t)NG * 1024 * 2;
    u16*   X3lo     = (u16*)  (ws + o); o += (size_t)NG * 1024 * 2;
    u16*   X4hi     = (u16*)  (ws + o); o += (size_t)NG * 512 * 2;
    u16*   X4lo     = (u16*)  (ws + o); o += (size_t)NG * 512 * 2;
    (void)ws_size; (void)in_sizes; (void)n_in; (void)out_size;

    PrepIn pin;
    for (int i = 0; i < 14; i++) pin.p[i] = d_in[2 + i];
    k_prep2<<<dim3(566), dim3(256), 0, stream>>>(pin, canon, W2T, WTa, hg);

    const float *W1 = canon+cW1, *b1 = canon+cb1, *b2 = canon+cb2;
    const float *ba = canon+cba, *bb = canon+cbb, *bc = canon+cbc, *bd = canon+cbd;
    const float *We = canon+cWe, *be = canon+cbe;

    // layer-1 + bucketing
    k_l1<<<dim3(NG), dim3(256), 0, stream>>>(
        src, dst, W1, b1, invIn, h1sT, edgeBuf, cntQ);

    // layer-2 conv + pool, (g,q) blocks, XCD-swizzled
    k_quarter<<<dim3(NG*4), dim3(256), 0, stream>>>(
        edgeBuf, cntQ, h1sT, W2T, invIn, b2, hg);

    // MLP (32x32 tiles, more blocks)
    k_mlp6<128,  true ><<<dim3(16, 16), dim3(512), 0, stream>>>(hg,   nullptr, WTa + T_Wa, ba, X1hi, X1lo, 512);
    k_mlp6<512,  false><<<dim3(16, 32), dim3(512), 0, stream>>>(X1hi, X1lo,    WTa + T_Wb, bb, X2hi, X2lo, 1024);
    k_mlp6<1024, false><<<dim3(16, 32), dim3(512), 0, stream>>>(X2hi, X2lo,    WTa + T_Wc, bc, X3hi, X3lo, 1024);
    k_mlp6<1024, false><<<dim3(16, 16), dim3(512), 0, stream>>>(X3hi, X3lo,    WTa + T_Wd, bd, X4hi, X4lo, 512);

    // head + softmax
    k_head<<<dim3(NG), dim3(64), 0, stream>>>(X4hi, X4lo, We, be, d_out, (const u16*)d_in[2]);
}